// Round 1
// baseline (5164.764 us; speedup 1.0000x reference)
//
#include <hip/hip_runtime.h>
#include <hip/hip_bf16.h>

#define NFACT 4
#define DEMB 64

__device__ __forceinline__ float4 softmax4(float4 a) {
    float m = fmaxf(fmaxf(a.x, a.y), fmaxf(a.z, a.w));
    float ex = __expf(a.x - m);
    float ey = __expf(a.y - m);
    float ez = __expf(a.z - m);
    float ew = __expf(a.w - m);
    float inv = 1.0f / (ex + ey + ez + ew);
    return make_float4(ex * inv, ey * inv, ez * inv, ew * inv);
}

__global__ void init_A_kernel(float4* __restrict__ A, int E) {
    int e = blockIdx.x * blockDim.x + threadIdx.x;
    if (e < E) A[e] = make_float4(1.f, 1.f, 1.f, 1.f);
}

// concat user/item embeddings into x, and also into acc (= ego0 term of the mean)
__global__ void concat_copy_kernel(const float* __restrict__ u, const float* __restrict__ it,
                                   float* __restrict__ x, float* __restrict__ acc,
                                   int nu_elems, int total) {
    int i = blockIdx.x * blockDim.x + threadIdx.x;
    if (i >= total) return;
    float v = (i < nu_elems) ? u[i] : it[i - nu_elems];
    x[i] = v;
    acc[i] = v;
}

// scores = softmax(A) per edge; rowsum[h[e]][f] += scores[f]
__global__ void rowsum_kernel(const float4* __restrict__ A, const int* __restrict__ h,
                              float* __restrict__ rowsum, int E) {
    int e = blockIdx.x * blockDim.x + threadIdx.x;
    if (e >= E) return;
    float4 p = softmax4(A[e]);
    int hh = h[e];
    atomicAdd(&rowsum[hh * 4 + 0], p.x);
    atomicAdd(&rowsum[hh * 4 + 1], p.y);
    atomicAdd(&rowsum[hh * 4 + 2], p.z);
    atomicAdd(&rowsum[hh * 4 + 3], p.w);
}

// in-place rowsum -> d_col = 1/sqrt(rowsum)
__global__ void dcol_kernel(float* __restrict__ rs, int n) {
    int i = blockIdx.x * blockDim.x + threadIdx.x;
    if (i < n) rs[i] = 1.0f / sqrtf(rs[i]);
}

// one 64-lane wave per edge: out[h[e]][j] += score[f]*d_col[t[e]][f]*x[t[e]][j]
__global__ void message_kernel(const float4* __restrict__ A, const int* __restrict__ h,
                               const int* __restrict__ t, const float* __restrict__ dcol,
                               const float* __restrict__ x, float* __restrict__ out, int E) {
    int idx = blockIdx.x * blockDim.x + threadIdx.x;
    int e = idx >> 6;
    if (e >= E) return;
    int j = idx & 63;
    int f = j >> 4;
    float4 p4 = softmax4(A[e]);
    float p = (f == 0) ? p4.x : (f == 1) ? p4.y : (f == 2) ? p4.z : p4.w;
    int tt = t[e];
    int hh = h[e];
    float s = p * dcol[tt * 4 + f];
    float val = s * x[(size_t)tt * DEMB + j];
    atomicAdd(&out[(size_t)hh * DEMB + j], val);
}

// out[n][j] *= d_col[n][j>>4]
__global__ void scale_kernel(float* __restrict__ out, const float* __restrict__ dcol, int total) {
    int i = blockIdx.x * blockDim.x + threadIdx.x;
    if (i >= total) return;
    int n = i >> 6;
    int f = (i >> 4) & 3;
    out[i] *= dcol[n * 4 + f];
}

// one wave per edge: A[e][f] += sum_df( l2norm(out[h])_f * tanh(l2norm(x[t])_f) )
__global__ void routing_kernel(const float* __restrict__ out, const float* __restrict__ x,
                               const int* __restrict__ h, const int* __restrict__ t,
                               float* __restrict__ A, int E) {
    int idx = blockIdx.x * blockDim.x + threadIdx.x;
    int e = idx >> 6;
    if (e >= E) return;
    int j = idx & 63;
    int hh = h[e];
    int tt = t[e];
    float ho = out[(size_t)hh * DEMB + j];
    float ta = x[(size_t)tt * DEMB + j];
    float hs = ho * ho;
    float ts = ta * ta;
#pragma unroll
    for (int off = 8; off >= 1; off >>= 1) {
        hs += __shfl_xor(hs, off);
        ts += __shfl_xor(ts, off);
    }
    float hn = ho / fmaxf(sqrtf(hs), 1e-12f);
    float tn = ta / fmaxf(sqrtf(ts), 1e-12f);
    float d = hn * tanhf(tn);
#pragma unroll
    for (int off = 8; off >= 1; off >>= 1) d += __shfl_xor(d, off);
    if ((j & 15) == 0) A[(size_t)e * 4 + (j >> 4)] += d;
}

__global__ void acc_kernel(float* __restrict__ acc, const float* __restrict__ v, int n) {
    int i = blockIdx.x * blockDim.x + threadIdx.x;
    if (i < n) acc[i] += v[i];
}

__global__ void mean_kernel(float* __restrict__ acc, int n) {
    int i = blockIdx.x * blockDim.x + threadIdx.x;
    if (i < n) acc[i] *= (1.0f / 3.0f);
}

extern "C" void kernel_launch(void* const* d_in, const int* in_sizes, int n_in,
                              void* d_out, int out_size, void* d_ws, size_t ws_size,
                              hipStream_t stream) {
    const float* user_emb = (const float*)d_in[0];
    const float* item_emb = (const float*)d_in[1];
    const int* h = (const int*)d_in[2];
    const int* t = (const int*)d_in[3];

    const int nu_elems = in_sizes[0];          // n_users * 64
    const int ni_elems = in_sizes[1];          // n_items * 64
    const int total = nu_elems + ni_elems;     // N * 64
    const int N = total / DEMB;
    const int E = in_sizes[2];

    float* acc = (float*)d_out;                // accumulator for the mean lives in d_out

    char* ws = (char*)d_ws;
    float* buf0 = (float*)ws;                                  // x
    float* buf1 = buf0 + (size_t)total;                        // out
    float4* A = (float4*)(buf1 + (size_t)total);               // routing logits [E][4]
    float* rowsum = (float*)(A + (size_t)E);                   // rowsum / d_col [N][4]

    const int BLK = 256;
    const int gE = (E + BLK - 1) / BLK;
    const int gTot = (total + BLK - 1) / BLK;
    const int gEdgeWave = (int)(((size_t)E * 64 + BLK - 1) / BLK);
    const int gN4 = (N * 4 + BLK - 1) / BLK;

    init_A_kernel<<<gE, BLK, 0, stream>>>(A, E);
    concat_copy_kernel<<<gTot, BLK, 0, stream>>>(user_emb, item_emb, buf0, acc, nu_elems, total);

    float* x = buf0;
    float* out = buf1;

    for (int layer = 0; layer < 2; ++layer) {
        for (int it = 0; it < 2; ++it) {
            hipMemsetAsync(rowsum, 0, (size_t)N * 4 * sizeof(float), stream);
            rowsum_kernel<<<gE, BLK, 0, stream>>>(A, h, rowsum, E);
            dcol_kernel<<<gN4, BLK, 0, stream>>>(rowsum, N * 4);
            hipMemsetAsync(out, 0, (size_t)total * sizeof(float), stream);
            message_kernel<<<gEdgeWave, BLK, 0, stream>>>(A, h, t, rowsum, x, out, E);
            scale_kernel<<<gTot, BLK, 0, stream>>>(out, rowsum, total);
            routing_kernel<<<gEdgeWave, BLK, 0, stream>>>(out, x, h, t, (float*)A, E);
        }
        acc_kernel<<<gTot, BLK, 0, stream>>>(acc, out, total);
        float* tmp = x; x = out; out = tmp;
    }
    mean_kernel<<<gTot, BLK, 0, stream>>>(acc, total);
}

// Round 2
// 3114.159 us; speedup vs baseline: 1.6585x; 1.6585x over previous
//
#include <hip/hip_runtime.h>
#include <hip/hip_bf16.h>

#define DEMB 64
typedef unsigned short u16;

__device__ __forceinline__ float4 softmax4(float4 a) {
    float m = fmaxf(fmaxf(a.x, a.y), fmaxf(a.z, a.w));
    float ex = __expf(a.x - m);
    float ey = __expf(a.y - m);
    float ez = __expf(a.z - m);
    float ew = __expf(a.w - m);
    float inv = 1.0f / (ex + ey + ez + ew);
    return make_float4(ex * inv, ey * inv, ez * inv, ew * inv);
}

__device__ __forceinline__ float fast_tanh(float a) {
    // tanh(a) = 1 - 2/(exp(2a)+1); a bounded in [-1,1] here (normalized input)
    float e = __expf(2.0f * a);
    return 1.0f - 2.0f / (e + 1.0f);
}

__device__ __forceinline__ float bf2f(u16 u) {
    union { unsigned int i; float f; } c; c.i = ((unsigned int)u) << 16; return c.f;
}
__device__ __forceinline__ u16 f2bf(float f) {
    union { float f; unsigned int i; } c; c.f = f;
    unsigned int r = c.i + 0x7FFF + ((c.i >> 16) & 1);
    return (u16)(r >> 16);
}

__global__ void init_A_kernel(float4* __restrict__ A, int E) {
    int e = blockIdx.x * blockDim.x + threadIdx.x;
    if (e < E) A[e] = make_float4(1.f, 1.f, 1.f, 1.f);
}

__global__ void concat_copy_kernel(const float* __restrict__ u, const float* __restrict__ it,
                                   float* __restrict__ x, float* __restrict__ acc,
                                   int nu_elems, int total) {
    int i = blockIdx.x * blockDim.x + threadIdx.x;
    if (i >= total) return;
    float v = (i < nu_elems) ? u[i] : it[i - nu_elems];
    x[i] = v;
    acc[i] = v;
}

// ---------------- CSR build ----------------
__global__ void count_kernel(const int* __restrict__ h, int* __restrict__ counts, int E) {
    int e = blockIdx.x * blockDim.x + threadIdx.x;
    if (e < E) atomicAdd(&counts[h[e]], 1);
}

__global__ void scan1_kernel(const int* __restrict__ counts, int* __restrict__ exc,
                             int* __restrict__ bsum, int N) {
    __shared__ int s[256];
    int tid = threadIdx.x;
    int i = blockIdx.x * 256 + tid;
    int v = (i < N) ? counts[i] : 0;
    s[tid] = v;
    __syncthreads();
    for (int off = 1; off < 256; off <<= 1) {
        int a = (tid >= off) ? s[tid - off] : 0;
        __syncthreads();
        s[tid] += a;
        __syncthreads();
    }
    if (i < N) exc[i] = s[tid] - v;
    if (tid == 255) bsum[blockIdx.x] = s[255];
}

__global__ void scan2_kernel(int* __restrict__ bsum, int nb) {
    if (threadIdx.x == 0 && blockIdx.x == 0) {
        int run = 0;
        for (int b = 0; b < nb; ++b) { int t = bsum[b]; bsum[b] = run; run += t; }
    }
}

__global__ void scan3_kernel(const int* __restrict__ exc, const int* __restrict__ bsum,
                             int* __restrict__ off, int N, int E) {
    int i = blockIdx.x * blockDim.x + threadIdx.x;
    if (i < N) off[i] = exc[i] + bsum[i >> 8];
    if (i == 0) off[N] = E;
}

__global__ void fill_kernel(const int* __restrict__ h, const int* __restrict__ t,
                            int* __restrict__ cur, int* __restrict__ csr_e,
                            int* __restrict__ csr_t, int E) {
    int e = blockIdx.x * blockDim.x + threadIdx.x;
    if (e >= E) return;
    int p = atomicAdd(&cur[h[e]], 1);
    csr_e[p] = e;
    csr_t[p] = t[e];
}

// ---------------- per-iteration kernels ----------------
// scores = softmax(A) per edge; rowsum[h[e]][f] += scores[f]
__global__ void rowsum_kernel(const float4* __restrict__ A, const int* __restrict__ h,
                              float* __restrict__ rowsum, int E) {
    int e = blockIdx.x * blockDim.x + threadIdx.x;
    if (e >= E) return;
    float4 p = softmax4(A[e]);
    int hh = h[e];
    atomicAdd(&rowsum[hh * 4 + 0], p.x);
    atomicAdd(&rowsum[hh * 4 + 1], p.y);
    atomicAdd(&rowsum[hh * 4 + 2], p.z);
    atomicAdd(&rowsum[hh * 4 + 3], p.w);
}

__global__ void dcol_kernel(float* __restrict__ rs, int n) {
    int i = blockIdx.x * blockDim.x + threadIdx.x;
    if (i < n) rs[i] = 1.0f / sqrtf(rs[i]);
}

// c[e][f] = softmax(A[e])[f] * dcol[t[e]][f]
__global__ void coef_kernel(const float4* __restrict__ A, const int* __restrict__ t,
                            const float4* __restrict__ dcol, float4* __restrict__ coef, int E) {
    int e = blockIdx.x * blockDim.x + threadIdx.x;
    if (e >= E) return;
    float4 p = softmax4(A[e]);
    float4 dv = dcol[t[e]];
    coef[e] = make_float4(p.x * dv.x, p.y * dv.y, p.z * dv.z, p.w * dv.w);
}

// tail table: tailt[n][j] = bf16( tanh( x[n][j] / ||x[n] factor||_2 ) )
__global__ void tail_kernel(const float* __restrict__ x, u16* __restrict__ tailt, int total) {
    int i = blockIdx.x * blockDim.x + threadIdx.x;
    if (i >= total) return;
    float v = x[i];
    float s = v * v;
#pragma unroll
    for (int off = 8; off >= 1; off >>= 1) s += __shfl_xor(s, off);
    float nr = fmaxf(sqrtf(s), 1e-12f);
    tailt[i] = f2bf(fast_tanh(v / nr));
}

// one 64-lane wave per node: out[n][j] = dcol[n][f] * sum_{e in CSR[n]} coef[e][f]*x[t[e]][j]
// epilogue: headn[n][j] = bf16( out[n][j] / ||out[n] factor|| )
__global__ void message_kernel(const int* __restrict__ off, const int* __restrict__ csr_e,
                               const int* __restrict__ csr_t, const float* __restrict__ coef,
                               const float* __restrict__ x, const float* __restrict__ dcol,
                               float* __restrict__ out, u16* __restrict__ headn,
                               int N, int writeHead) {
    int gid = blockIdx.x * blockDim.x + threadIdx.x;
    int n = gid >> 6;
    if (n >= N) return;
    int j = gid & 63;
    int f = j >> 4;
    int s = off[n], e = off[n + 1];
    float acc = 0.0f;
    for (int k = s; k < e; ++k) {
        int ed = csr_e[k];
        int tt = csr_t[k];
        float c = coef[(size_t)ed * 4 + f];
        acc += c * x[(size_t)tt * DEMB + j];
    }
    float o = acc * dcol[n * 4 + f];
    out[(size_t)n * DEMB + j] = o;
    if (writeHead) {
        float ss = o * o;
#pragma unroll
        for (int offv = 8; offv >= 1; offv >>= 1) ss += __shfl_xor(ss, offv);
        float nr = fmaxf(sqrtf(ss), 1e-12f);
        headn[(size_t)n * DEMB + j] = f2bf(o / nr);
    }
}

// 16 lanes per edge: A[e][f] += dot16(headn[h[e]], tailt[t[e]]) per factor
__global__ void routing_kernel(const u16* __restrict__ headn, const u16* __restrict__ tailt,
                               const int* __restrict__ h, const int* __restrict__ t,
                               float* __restrict__ A, int E) {
    long long gid = (long long)blockIdx.x * blockDim.x + threadIdx.x;
    int e = (int)(gid >> 4);
    if (e >= E) return;
    int k = (int)(gid & 15);
    int f = k >> 2;
    int hh = h[e], tt = t[e];
    const ushort4* hp = (const ushort4*)headn;
    const ushort4* tp = (const ushort4*)tailt;
    ushort4 hv = hp[(size_t)hh * 16 + k];
    ushort4 tv = tp[(size_t)tt * 16 + k];
    float d = bf2f(hv.x) * bf2f(tv.x) + bf2f(hv.y) * bf2f(tv.y) +
              bf2f(hv.z) * bf2f(tv.z) + bf2f(hv.w) * bf2f(tv.w);
    d += __shfl_xor(d, 1);
    d += __shfl_xor(d, 2);
    if ((k & 3) == 0) A[(size_t)e * 4 + f] += d;
}

__global__ void acc_kernel(float* __restrict__ acc, const float* __restrict__ v, int n) {
    int i = blockIdx.x * blockDim.x + threadIdx.x;
    if (i < n) acc[i] += v[i];
}

__global__ void mean_kernel(float* __restrict__ acc, int n) {
    int i = blockIdx.x * blockDim.x + threadIdx.x;
    if (i < n) acc[i] *= (1.0f / 3.0f);
}

extern "C" void kernel_launch(void* const* d_in, const int* in_sizes, int n_in,
                              void* d_out, int out_size, void* d_ws, size_t ws_size,
                              hipStream_t stream) {
    const float* user_emb = (const float*)d_in[0];
    const float* item_emb = (const float*)d_in[1];
    const int* h = (const int*)d_in[2];
    const int* t = (const int*)d_in[3];

    const int nu_elems = in_sizes[0];
    const int ni_elems = in_sizes[1];
    const int total = nu_elems + ni_elems;   // N * 64
    const int N = total / DEMB;
    const int E = in_sizes[2];
    const int nb = (N + 255) / 256;

    float* acc = (float*)d_out;

    // ---- workspace layout (all section sizes multiple of 16 bytes) ----
    float* x    = (float*)d_ws;                 // total
    float* out  = x + (size_t)total;            // total
    float* A    = out + (size_t)total;          // 4E
    float* coef = A + (size_t)4 * E;            // 4E
    float* dcol = coef + (size_t)4 * E;         // 4N
    u16* headn  = (u16*)(dcol + (size_t)4 * N); // total u16
    u16* tailt  = headn + (size_t)total;        // total u16
    int* counts = (int*)(tailt + (size_t)total);// N
    int* off    = counts + N;                   // N+4 (padded)
    int* cur    = off + N + 4;                  // N
    int* exc    = cur + N;                      // N
    int* bsum   = exc + N;                      // nb padded to 4
    int* csr_e  = bsum + ((nb + 3) & ~3);       // E
    int* csr_t  = csr_e + E;                    // E

    const int BLK = 256;
    const int gE = (E + BLK - 1) / BLK;
    const int gTot = (total + BLK - 1) / BLK;
    const int gN4 = (N * 4 + BLK - 1) / BLK;
    const int gNodeWave = (N * 64 + BLK - 1) / BLK;
    const int gEdge16 = (int)(((long long)E * 16 + BLK - 1) / BLK);

    init_A_kernel<<<gE, BLK, 0, stream>>>((float4*)A, E);
    concat_copy_kernel<<<gTot, BLK, 0, stream>>>(user_emb, item_emb, x, acc, nu_elems, total);

    // CSR build (h is fixed input; rebuilt every call for determinism)
    hipMemsetAsync(counts, 0, (size_t)N * sizeof(int), stream);
    count_kernel<<<gE, BLK, 0, stream>>>(h, counts, E);
    scan1_kernel<<<nb, 256, 0, stream>>>(counts, exc, bsum, N);
    scan2_kernel<<<1, 64, 0, stream>>>(bsum, nb);
    scan3_kernel<<<(N + BLK - 1) / BLK, BLK, 0, stream>>>(exc, bsum, off, N, E);
    hipMemcpyAsync(cur, off, (size_t)N * sizeof(int), hipMemcpyDeviceToDevice, stream);
    fill_kernel<<<gE, BLK, 0, stream>>>(h, t, cur, csr_e, csr_t, E);

    float* xb = x;
    float* ob = out;

    for (int layer = 0; layer < 2; ++layer) {
        tail_kernel<<<gTot, BLK, 0, stream>>>(xb, tailt, total);
        for (int it = 0; it < 2; ++it) {
            bool last = (layer == 1 && it == 1);
            hipMemsetAsync(dcol, 0, (size_t)N * 4 * sizeof(float), stream);
            rowsum_kernel<<<gE, BLK, 0, stream>>>((const float4*)A, h, dcol, E);
            dcol_kernel<<<gN4, BLK, 0, stream>>>(dcol, N * 4);
            coef_kernel<<<gE, BLK, 0, stream>>>((const float4*)A, t, (const float4*)dcol,
                                                (float4*)coef, E);
            message_kernel<<<gNodeWave, BLK, 0, stream>>>(off, csr_e, csr_t, coef, xb, dcol,
                                                          ob, headn, N, last ? 0 : 1);
            if (!last)
                routing_kernel<<<gEdge16, BLK, 0, stream>>>(headn, tailt, h, t, A, E);
        }
        acc_kernel<<<gTot, BLK, 0, stream>>>(acc, ob, total);
        float* tmp = xb; xb = ob; ob = tmp;
    }
    mean_kernel<<<gTot, BLK, 0, stream>>>(acc, total);
}

// Round 3
// 2153.043 us; speedup vs baseline: 2.3988x; 1.4464x over previous
//
#include <hip/hip_runtime.h>
#include <hip/hip_bf16.h>

#define DEMB 64
typedef unsigned short u16;

__device__ __forceinline__ float4 softmax4(float4 a) {
    float m = fmaxf(fmaxf(a.x, a.y), fmaxf(a.z, a.w));
    float ex = __expf(a.x - m);
    float ey = __expf(a.y - m);
    float ez = __expf(a.z - m);
    float ew = __expf(a.w - m);
    float inv = 1.0f / (ex + ey + ez + ew);
    return make_float4(ex * inv, ey * inv, ez * inv, ew * inv);
}

__device__ __forceinline__ float fast_tanh(float a) {
    float e = __expf(2.0f * a);
    return 1.0f - 2.0f / (e + 1.0f);
}

__device__ __forceinline__ float bf2f(u16 u) {
    union { unsigned int i; float f; } c; c.i = ((unsigned int)u) << 16; return c.f;
}
__device__ __forceinline__ u16 f2bf(float f) {
    union { float f; unsigned int i; } c; c.f = f;
    unsigned int r = c.i + 0x7FFF + ((c.i >> 16) & 1);
    return (u16)(r >> 16);
}

__global__ void init_A_kernel(float4* __restrict__ A, int E) {
    int e = blockIdx.x * blockDim.x + threadIdx.x;
    if (e < E) A[e] = make_float4(1.f, 1.f, 1.f, 1.f);
}

__global__ void concat_copy_kernel(const float* __restrict__ u, const float* __restrict__ it,
                                   float* __restrict__ x, float* __restrict__ acc,
                                   int nu_elems, int total) {
    int i = blockIdx.x * blockDim.x + threadIdx.x;
    if (i >= total) return;
    float v = (i < nu_elems) ? u[i] : it[i - nu_elems];
    x[i] = v;
    acc[i] = v;
}

// ---------------- CSR build (by h) ----------------
__global__ void count_kernel(const int* __restrict__ h, int* __restrict__ counts, int E) {
    int e = blockIdx.x * blockDim.x + threadIdx.x;
    if (e < E) atomicAdd(&counts[h[e]], 1);
}

__global__ void scan1_kernel(const int* __restrict__ counts, int* __restrict__ exc,
                             int* __restrict__ bsum, int N) {
    __shared__ int s[256];
    int tid = threadIdx.x;
    int i = blockIdx.x * 256 + tid;
    int v = (i < N) ? counts[i] : 0;
    s[tid] = v;
    __syncthreads();
    for (int off = 1; off < 256; off <<= 1) {
        int a = (tid >= off) ? s[tid - off] : 0;
        __syncthreads();
        s[tid] += a;
        __syncthreads();
    }
    if (i < N) exc[i] = s[tid] - v;
    if (tid == 255) bsum[blockIdx.x] = s[255];
}

__global__ void scan2_kernel(int* __restrict__ bsum, int nb) {
    if (threadIdx.x == 0 && blockIdx.x == 0) {
        int run = 0;
        for (int b = 0; b < nb; ++b) { int t = bsum[b]; bsum[b] = run; run += t; }
    }
}

__global__ void scan3_kernel(const int* __restrict__ exc, const int* __restrict__ bsum,
                             int* __restrict__ off, int N, int E) {
    int i = blockIdx.x * blockDim.x + threadIdx.x;
    if (i < N) off[i] = exc[i] + bsum[i >> 8];
    if (i == 0) off[N] = E;
}

__global__ void fill_kernel(const int* __restrict__ h, const int* __restrict__ t,
                            int* __restrict__ cur, int* __restrict__ csr_t, int E) {
    int e = blockIdx.x * blockDim.x + threadIdx.x;
    if (e >= E) return;
    int p = atomicAdd(&cur[h[e]], 1);
    csr_t[p] = t[e];
}

// ---------------- per-iteration kernels ----------------
// one wave per node: dcol[n][f] = rsqrt( sum_{k in CSR[n]} softmax4(A_csr[k])[f] )
// lane l handles edge-slot (l>>2), factor (l&3): A_csr read is fully coalesced.
__global__ void dcol_kernel(const float* __restrict__ Acsr, const int* __restrict__ off,
                            float* __restrict__ dcol, int N) {
    int gid = blockIdx.x * blockDim.x + threadIdx.x;
    int n = gid >> 6;
    if (n >= N) return;
    int l = gid & 63;
    int s = off[n], e = off[n + 1];
    float sumf = 0.f;
    for (int base = s; base < e; base += 16) {
        int k = base + (l >> 2);
        float a = (k < e) ? Acsr[(size_t)k * 4 + (l & 3)] : 0.0f;
        float m = a;
        m = fmaxf(m, __shfl_xor(m, 1));
        m = fmaxf(m, __shfl_xor(m, 2));
        float ex = __expf(a - m);
        float se = ex;
        se += __shfl_xor(se, 1);
        se += __shfl_xor(se, 2);
        float p = ex / se;
        sumf += (k < e) ? p : 0.f;
    }
#pragma unroll
    for (int o = 4; o <= 32; o <<= 1) sumf += __shfl_xor(sumf, o);
    if (l < 4) dcol[n * 4 + l] = rsqrtf(sumf);
}

// per-layer tables from current ego x:
//   xbf[i]   = bf16(x[i])
//   tailt[i] = bf16( tanh( x[i] / ||x factor-chunk||_2 ) )
__global__ void tail_kernel(const float* __restrict__ x, u16* __restrict__ tailt,
                            u16* __restrict__ xbf, int total) {
    int i = blockIdx.x * blockDim.x + threadIdx.x;
    if (i >= total) return;
    float v = x[i];
    xbf[i] = f2bf(v);
    float s = v * v;
#pragma unroll
    for (int off = 8; off >= 1; off >>= 1) s += __shfl_xor(s, off);
    float nr = fmaxf(sqrtf(s), 1e-12f);
    tailt[i] = f2bf(fast_tanh(v / nr));
}

// one 64-lane wave per node n (lane j = column, f = j>>4):
//  loop1: out[n][j] = dcol[n][f] * sum_k softmax(A_csr[k])[f] * dcol[t_k][f] * xbf[t_k][j]
//  epilogue: head[j] = out[n][j]/||out[n] factor||  (registers only)
//  loop2 (if doRouting): A_csr[k][f] += dot16(head_f, tailt[t_k]_f)
__global__ void message_routing_kernel(const int* __restrict__ off, const int* __restrict__ csr_t,
                                       float* __restrict__ Acsr, const u16* __restrict__ xbf,
                                       const u16* __restrict__ tailt, const float* __restrict__ dcol,
                                       float* __restrict__ out, int N, int doRouting) {
    int gid = blockIdx.x * blockDim.x + threadIdx.x;
    int n = gid >> 6;
    if (n >= N) return;
    int j = gid & 63;
    int f = j >> 4;
    int s = off[n], e = off[n + 1];
    const float4* A4 = (const float4*)Acsr;

    float acc = 0.f;
    for (int k = s; k < e; ++k) {
        int tt = csr_t[k];
        float4 p = softmax4(A4[k]);
        float pf = (f == 0) ? p.x : (f == 1) ? p.y : (f == 2) ? p.z : p.w;
        float c = pf * dcol[tt * 4 + f];
        acc += c * bf2f(xbf[(size_t)tt * DEMB + j]);
    }
    float o = acc * dcol[n * 4 + f];
    out[(size_t)n * DEMB + j] = o;

    if (!doRouting) return;
    float ss = o * o;
#pragma unroll
    for (int w = 1; w <= 8; w <<= 1) ss += __shfl_xor(ss, w);
    float head = o / fmaxf(sqrtf(ss), 1e-12f);

    for (int k = s; k < e; ++k) {
        int tt = csr_t[k];
        float d = head * bf2f(tailt[(size_t)tt * DEMB + j]);
#pragma unroll
        for (int w = 1; w <= 8; w <<= 1) d += __shfl_xor(d, w);
        if ((j & 15) == 0) Acsr[(size_t)k * 4 + f] += d;
    }
}

__global__ void acc_kernel(float* __restrict__ acc, const float* __restrict__ v, int n) {
    int i = blockIdx.x * blockDim.x + threadIdx.x;
    if (i < n) acc[i] += v[i];
}

__global__ void mean_kernel(float* __restrict__ acc, int n) {
    int i = blockIdx.x * blockDim.x + threadIdx.x;
    if (i < n) acc[i] *= (1.0f / 3.0f);
}

extern "C" void kernel_launch(void* const* d_in, const int* in_sizes, int n_in,
                              void* d_out, int out_size, void* d_ws, size_t ws_size,
                              hipStream_t stream) {
    const float* user_emb = (const float*)d_in[0];
    const float* item_emb = (const float*)d_in[1];
    const int* h = (const int*)d_in[2];
    const int* t = (const int*)d_in[3];

    const int nu_elems = in_sizes[0];
    const int ni_elems = in_sizes[1];
    const int total = nu_elems + ni_elems;   // N * 64
    const int N = total / DEMB;
    const int E = in_sizes[2];
    const int nb = (N + 255) / 256;

    float* acc = (float*)d_out;

    // ---- workspace layout ----
    float* x     = (float*)d_ws;                  // total f32
    float* out   = x + (size_t)total;             // total f32
    float* Acsr  = out + (size_t)total;           // 4E f32 (CSR-ordered routing logits)
    float* dcol  = Acsr + (size_t)4 * E;          // 4N f32
    u16* xbf     = (u16*)(dcol + (size_t)4 * N);  // total u16
    u16* tailt   = xbf + (size_t)total;           // total u16
    int* counts  = (int*)(tailt + (size_t)total); // N
    int* off     = counts + N;                    // N+4
    int* cur     = off + N + 4;                   // N
    int* exc     = cur + N;                       // N
    int* bsum    = exc + N;                       // nb (padded)
    int* csr_t   = bsum + ((nb + 3) & ~3);        // E

    const int BLK = 256;
    const int gE = (E + BLK - 1) / BLK;
    const int gTot = (total + BLK - 1) / BLK;
    const int gNodeWave = (N * 64 + BLK - 1) / BLK;

    init_A_kernel<<<gE, BLK, 0, stream>>>((float4*)Acsr, E);
    concat_copy_kernel<<<gTot, BLK, 0, stream>>>(user_emb, item_emb, x, acc, nu_elems, total);

    // CSR build
    hipMemsetAsync(counts, 0, (size_t)N * sizeof(int), stream);
    count_kernel<<<gE, BLK, 0, stream>>>(h, counts, E);
    scan1_kernel<<<nb, 256, 0, stream>>>(counts, exc, bsum, N);
    scan2_kernel<<<1, 64, 0, stream>>>(bsum, nb);
    scan3_kernel<<<(N + BLK - 1) / BLK, BLK, 0, stream>>>(exc, bsum, off, N, E);
    hipMemcpyAsync(cur, off, (size_t)N * sizeof(int), hipMemcpyDeviceToDevice, stream);
    fill_kernel<<<gE, BLK, 0, stream>>>(h, t, cur, csr_t, E);

    float* xb = x;
    float* ob = out;

    for (int layer = 0; layer < 2; ++layer) {
        tail_kernel<<<gTot, BLK, 0, stream>>>(xb, tailt, xbf, total);
        for (int it = 0; it < 2; ++it) {
            bool last = (layer == 1 && it == 1);
            dcol_kernel<<<gNodeWave, BLK, 0, stream>>>(Acsr, off, dcol, N);
            message_routing_kernel<<<gNodeWave, BLK, 0, stream>>>(off, csr_t, Acsr, xbf, tailt,
                                                                  dcol, ob, N, last ? 0 : 1);
        }
        acc_kernel<<<gTot, BLK, 0, stream>>>(acc, ob, total);
        float* tmp = xb; xb = ob; ob = tmp;
    }
    mean_kernel<<<gTot, BLK, 0, stream>>>(acc, total);
}

// Round 4
// 1145.276 us; speedup vs baseline: 4.5096x; 1.8799x over previous
//
#include <hip/hip_runtime.h>
#include <hip/hip_bf16.h>

#define DEMB 64
typedef unsigned short u16;

__device__ __forceinline__ float4 softmax4(float4 a) {
    float m = fmaxf(fmaxf(a.x, a.y), fmaxf(a.z, a.w));
    float ex = __expf(a.x - m);
    float ey = __expf(a.y - m);
    float ez = __expf(a.z - m);
    float ew = __expf(a.w - m);
    float inv = 1.0f / (ex + ey + ez + ew);
    return make_float4(ex * inv, ey * inv, ez * inv, ew * inv);
}

__device__ __forceinline__ float fast_tanh(float a) {
    float e = __expf(2.0f * a);
    return 1.0f - 2.0f / (e + 1.0f);
}

__device__ __forceinline__ float bf2f(u16 u) {
    union { unsigned int i; float f; } c; c.i = ((unsigned int)u) << 16; return c.f;
}
__device__ __forceinline__ u16 f2bf(float f) {
    union { float f; unsigned int i; } c; c.f = f;
    unsigned int r = c.i + 0x7FFF + ((c.i >> 16) & 1);
    return (u16)(r >> 16);
}

__global__ void init_A_kernel(float4* __restrict__ A, int E) {
    int e = blockIdx.x * blockDim.x + threadIdx.x;
    if (e < E) A[e] = make_float4(1.f, 1.f, 1.f, 1.f);
}

__global__ void concat_copy_kernel(const float* __restrict__ u, const float* __restrict__ it,
                                   float* __restrict__ x, float* __restrict__ acc,
                                   int nu_elems, int total) {
    int i = blockIdx.x * blockDim.x + threadIdx.x;
    if (i >= total) return;
    float v = (i < nu_elems) ? u[i] : it[i - nu_elems];
    x[i] = v;
    acc[i] = v;
}

// ---------------- CSR build (by h) ----------------
__global__ void count_kernel(const int* __restrict__ h, int* __restrict__ counts, int E) {
    int e = blockIdx.x * blockDim.x + threadIdx.x;
    if (e < E) atomicAdd(&counts[h[e]], 1);
}

__global__ void scan1_kernel(const int* __restrict__ counts, int* __restrict__ exc,
                             int* __restrict__ bsum, int N) {
    __shared__ int s[256];
    int tid = threadIdx.x;
    int i = blockIdx.x * 256 + tid;
    int v = (i < N) ? counts[i] : 0;
    s[tid] = v;
    __syncthreads();
    for (int off = 1; off < 256; off <<= 1) {
        int a = (tid >= off) ? s[tid - off] : 0;
        __syncthreads();
        s[tid] += a;
        __syncthreads();
    }
    if (i < N) exc[i] = s[tid] - v;
    if (tid == 255) bsum[blockIdx.x] = s[255];
}

__global__ void scan2_kernel(int* __restrict__ bsum, int nb) {
    if (threadIdx.x == 0 && blockIdx.x == 0) {
        int run = 0;
        for (int b = 0; b < nb; ++b) { int t = bsum[b]; bsum[b] = run; run += t; }
    }
}

__global__ void scan3_kernel(const int* __restrict__ exc, const int* __restrict__ bsum,
                             int* __restrict__ off, int N, int E) {
    int i = blockIdx.x * blockDim.x + threadIdx.x;
    if (i < N) off[i] = exc[i] + bsum[i >> 8];
    if (i == 0) off[N] = E;
}

__global__ void fill_kernel(const int* __restrict__ h, const int* __restrict__ t,
                            int* __restrict__ cur, int* __restrict__ csr_t, int E) {
    int e = blockIdx.x * blockDim.x + threadIdx.x;
    if (e >= E) return;
    int p = atomicAdd(&cur[h[e]], 1);
    csr_t[p] = t[e];
}

// ---------------- per-iteration kernels ----------------
// one wave per node: dcol[n][f] = rsqrt( sum_{k in CSR[n]} softmax4(A_csr[k])[f] )
__global__ void dcol_kernel(const float* __restrict__ Acsr, const int* __restrict__ off,
                            float* __restrict__ dcol, int N) {
    int gid = blockIdx.x * blockDim.x + threadIdx.x;
    int n = gid >> 6;
    if (n >= N) return;
    int l = gid & 63;
    int s = off[n], e = off[n + 1];
    float sumf = 0.f;
    for (int base = s; base < e; base += 16) {
        int k = base + (l >> 2);
        float a = (k < e) ? Acsr[(size_t)k * 4 + (l & 3)] : 0.0f;
        float m = a;
        m = fmaxf(m, __shfl_xor(m, 1));
        m = fmaxf(m, __shfl_xor(m, 2));
        float ex = __expf(a - m);
        float se = ex;
        se += __shfl_xor(se, 1);
        se += __shfl_xor(se, 2);
        float p = ex / se;
        sumf += (k < e) ? p : 0.f;
    }
#pragma unroll
    for (int o = 4; o <= 32; o <<= 1) sumf += __shfl_xor(sumf, o);
    if (l < 4) dcol[n * 4 + l] = rsqrtf(sumf);
}

// coef[k][f] = softmax4(Acsr[k])[f] * dcol[csr_t[k]][f]   (coalesced, CSR order)
__global__ void coef_kernel(const float4* __restrict__ A4, const int* __restrict__ csr_t,
                            const float4* __restrict__ dcol4, float4* __restrict__ coef4, int E) {
    int k = blockIdx.x * blockDim.x + threadIdx.x;
    if (k >= E) return;
    float4 p = softmax4(A4[k]);
    float4 dv = dcol4[csr_t[k]];
    coef4[k] = make_float4(p.x * dv.x, p.y * dv.y, p.z * dv.z, p.w * dv.w);
}

// per-layer tables from current ego x:
//   xbf[i]   = bf16(x[i])
//   tailt[i] = bf16( tanh( x[i] / ||x factor-chunk||_2 ) )
__global__ void tail_kernel(const float* __restrict__ x, u16* __restrict__ tailt,
                            u16* __restrict__ xbf, int total) {
    int i = blockIdx.x * blockDim.x + threadIdx.x;
    if (i >= total) return;
    float v = x[i];
    xbf[i] = f2bf(v);
    float s = v * v;
#pragma unroll
    for (int off = 8; off >= 1; off >>= 1) s += __shfl_xor(s, off);
    float nr = fmaxf(sqrtf(s), 1e-12f);
    tailt[i] = f2bf(fast_tanh(v / nr));
}

// One 64-lane wave per node, 4 edges per loop iteration.
// lane l: g = l>>4 (edge slot), m = l&15 (column quad: cols 4m..4m+3), f = m>>2.
// loop1: acc[j] = sum_k coef[k][f] * xbf[t_k][j]   (ushort4 gathers, 4 edges/iter)
// combine slots via shfl_xor(16,32) -> all lanes hold full row.
// epilogue: out[n] = dcol[n]*acc; head = out/||out_f|| (registers only).
// loop2: A_csr[k][f] += dot16(head_f, tailt[t_k]_f)  (quad shuffle reduce)
__global__ void message_routing_kernel(const int* __restrict__ off, const int* __restrict__ csr_t,
                                       float* __restrict__ Acsr, const float* __restrict__ coef,
                                       const u16* __restrict__ xbf, const u16* __restrict__ tailt,
                                       const float* __restrict__ dcol,
                                       float* __restrict__ out, int N, int doRouting) {
    int gid = blockIdx.x * blockDim.x + threadIdx.x;
    int n = gid >> 6;
    if (n >= N) return;
    int l = gid & 63;
    int g = l >> 4;
    int m = l & 15;
    int f = m >> 2;
    int s = off[n], e = off[n + 1];

    float a0 = 0.f, a1 = 0.f, a2 = 0.f, a3 = 0.f;
#pragma unroll 2
    for (int k = s; k < e; k += 4) {
        int ek = k + g;
        bool valid = ek < e;
        int ekc = valid ? ek : (e - 1);
        int tt = csr_t[ekc];
        float c = valid ? coef[(size_t)ekc * 4 + f] : 0.f;
        const ushort4 v = *(const ushort4*)(xbf + ((size_t)tt << 6) + (m << 2));
        a0 += c * bf2f(v.x);
        a1 += c * bf2f(v.y);
        a2 += c * bf2f(v.z);
        a3 += c * bf2f(v.w);
    }
    // combine the 4 edge slots -> every lane holds the full sums for its cols
    a0 += __shfl_xor(a0, 16); a1 += __shfl_xor(a1, 16);
    a2 += __shfl_xor(a2, 16); a3 += __shfl_xor(a3, 16);
    a0 += __shfl_xor(a0, 32); a1 += __shfl_xor(a1, 32);
    a2 += __shfl_xor(a2, 32); a3 += __shfl_xor(a3, 32);

    float dn = dcol[n * 4 + f];
    float o0 = a0 * dn, o1 = a1 * dn, o2 = a2 * dn, o3 = a3 * dn;
    if (l < 16) {
        *(float4*)(out + ((size_t)n << 6) + (m << 2)) = make_float4(o0, o1, o2, o3);
    }
    if (!doRouting) return;

    float ss = o0 * o0 + o1 * o1 + o2 * o2 + o3 * o3;
    ss += __shfl_xor(ss, 1);
    ss += __shfl_xor(ss, 2);
    float inv = 1.0f / fmaxf(sqrtf(ss), 1e-12f);
    float h0 = o0 * inv, h1 = o1 * inv, h2 = o2 * inv, h3 = o3 * inv;

#pragma unroll 2
    for (int k = s; k < e; k += 4) {
        int ek = k + g;
        bool valid = ek < e;
        int ekc = valid ? ek : (e - 1);
        int tt = csr_t[ekc];
        const ushort4 tv = *(const ushort4*)(tailt + ((size_t)tt << 6) + (m << 2));
        float d = h0 * bf2f(tv.x) + h1 * bf2f(tv.y) + h2 * bf2f(tv.z) + h3 * bf2f(tv.w);
        d += __shfl_xor(d, 1);
        d += __shfl_xor(d, 2);
        if (valid && (m & 3) == 0)
            Acsr[(size_t)ekc * 4 + f] += d;
    }
}

// acc += v; if final, acc = (acc + v) / 3
__global__ void acc_kernel(float* __restrict__ acc, const float* __restrict__ v, int n, int final_) {
    int i = blockIdx.x * blockDim.x + threadIdx.x;
    if (i >= n) return;
    float r = acc[i] + v[i];
    acc[i] = final_ ? r * (1.0f / 3.0f) : r;
}

extern "C" void kernel_launch(void* const* d_in, const int* in_sizes, int n_in,
                              void* d_out, int out_size, void* d_ws, size_t ws_size,
                              hipStream_t stream) {
    const float* user_emb = (const float*)d_in[0];
    const float* item_emb = (const float*)d_in[1];
    const int* h = (const int*)d_in[2];
    const int* t = (const int*)d_in[3];

    const int nu_elems = in_sizes[0];
    const int ni_elems = in_sizes[1];
    const int total = nu_elems + ni_elems;   // N * 64
    const int N = total / DEMB;
    const int E = in_sizes[2];
    const int nb = (N + 255) / 256;

    float* acc = (float*)d_out;

    // ---- workspace layout ----
    float* x     = (float*)d_ws;                  // total f32
    float* out   = x + (size_t)total;             // total f32
    float* Acsr  = out + (size_t)total;           // 4E f32 (CSR-ordered routing logits)
    float* coef  = Acsr + (size_t)4 * E;          // 4E f32
    float* dcol  = coef + (size_t)4 * E;          // 4N f32
    u16* xbf     = (u16*)(dcol + (size_t)4 * N);  // total u16
    u16* tailt   = xbf + (size_t)total;           // total u16
    int* counts  = (int*)(tailt + (size_t)total); // N
    int* off     = counts + N;                    // N+4
    int* cur     = off + N + 4;                   // N
    int* exc     = cur + N;                       // N
    int* bsum    = exc + N;                       // nb (padded)
    int* csr_t   = bsum + ((nb + 3) & ~3);        // E

    const int BLK = 256;
    const int gE = (E + BLK - 1) / BLK;
    const int gTot = (total + BLK - 1) / BLK;
    const int gNodeWave = (N * 64 + BLK - 1) / BLK;

    init_A_kernel<<<gE, BLK, 0, stream>>>((float4*)Acsr, E);
    concat_copy_kernel<<<gTot, BLK, 0, stream>>>(user_emb, item_emb, x, acc, nu_elems, total);

    // CSR build
    hipMemsetAsync(counts, 0, (size_t)N * sizeof(int), stream);
    count_kernel<<<gE, BLK, 0, stream>>>(h, counts, E);
    scan1_kernel<<<nb, 256, 0, stream>>>(counts, exc, bsum, N);
    scan2_kernel<<<1, 64, 0, stream>>>(bsum, nb);
    scan3_kernel<<<(N + BLK - 1) / BLK, BLK, 0, stream>>>(exc, bsum, off, N, E);
    hipMemcpyAsync(cur, off, (size_t)N * sizeof(int), hipMemcpyDeviceToDevice, stream);
    fill_kernel<<<gE, BLK, 0, stream>>>(h, t, cur, csr_t, E);

    float* xb = x;
    float* ob = out;

    for (int layer = 0; layer < 2; ++layer) {
        tail_kernel<<<gTot, BLK, 0, stream>>>(xb, tailt, xbf, total);
        for (int it = 0; it < 2; ++it) {
            bool last = (layer == 1 && it == 1);
            dcol_kernel<<<gNodeWave, BLK, 0, stream>>>(Acsr, off, dcol, N);
            coef_kernel<<<gE, BLK, 0, stream>>>((const float4*)Acsr, csr_t, (const float4*)dcol,
                                                (float4*)coef, E);
            message_routing_kernel<<<gNodeWave, BLK, 0, stream>>>(off, csr_t, Acsr, coef, xbf,
                                                                  tailt, dcol, ob, N, last ? 0 : 1);
        }
        acc_kernel<<<gTot, BLK, 0, stream>>>(acc, ob, total, layer == 1 ? 1 : 0);
        float* tmp = xb; xb = ob; ob = tmp;
    }
}

// Round 5
// 1054.253 us; speedup vs baseline: 4.8990x; 1.0863x over previous
//
#include <hip/hip_runtime.h>
#include <hip/hip_bf16.h>

#define DEMB 64
typedef unsigned short u16;

__device__ __forceinline__ float bf2f(u16 u) {
    union { unsigned int i; float f; } c; c.i = ((unsigned int)u) << 16; return c.f;
}
__device__ __forceinline__ u16 f2bf(float f) {
    union { float f; unsigned int i; } c; c.f = f;
    unsigned int r = c.i + 0x7FFF + ((c.i >> 16) & 1);
    return (u16)(r >> 16);
}

// Pade [3/2] tanh, |a|<=~1: abs err <= ~3.1e-4 (below bf16 rounding noise here)
__device__ __forceinline__ float ptanh(float a) {
    float a2 = a * a;
    return a * (15.0f + a2) * __builtin_amdgcn_rcpf(15.0f + 6.0f * a2);
}

__global__ void init_A_kernel(float4* __restrict__ A, int E) {
    int e = blockIdx.x * blockDim.x + threadIdx.x;
    if (e < E) A[e] = make_float4(1.f, 1.f, 1.f, 1.f);
}

__global__ void concat_copy_kernel(const float* __restrict__ u, const float* __restrict__ it,
                                   float* __restrict__ x, float* __restrict__ acc,
                                   int nu_elems, int total) {
    int i = blockIdx.x * blockDim.x + threadIdx.x;
    if (i >= total) return;
    float v = (i < nu_elems) ? u[i] : it[i - nu_elems];
    x[i] = v;
    acc[i] = v;
}

// ---------------- CSR build (by h) ----------------
__global__ void count_kernel(const int* __restrict__ h, int* __restrict__ counts, int E) {
    int e = blockIdx.x * blockDim.x + threadIdx.x;
    if (e < E) atomicAdd(&counts[h[e]], 1);
}

__global__ void scan1_kernel(const int* __restrict__ counts, int* __restrict__ exc,
                             int* __restrict__ bsum, int N) {
    __shared__ int s[256];
    int tid = threadIdx.x;
    int i = blockIdx.x * 256 + tid;
    int v = (i < N) ? counts[i] : 0;
    s[tid] = v;
    __syncthreads();
    for (int off = 1; off < 256; off <<= 1) {
        int a = (tid >= off) ? s[tid - off] : 0;
        __syncthreads();
        s[tid] += a;
        __syncthreads();
    }
    if (i < N) exc[i] = s[tid] - v;
    if (tid == 255) bsum[blockIdx.x] = s[255];
}

__global__ void scan2_kernel(int* __restrict__ bsum, int nb) {
    if (threadIdx.x == 0 && blockIdx.x == 0) {
        int run = 0;
        for (int b = 0; b < nb; ++b) { int t = bsum[b]; bsum[b] = run; run += t; }
    }
}

__global__ void scan3_kernel(const int* __restrict__ exc, const int* __restrict__ bsum,
                             int* __restrict__ off, int N, int E) {
    int i = blockIdx.x * blockDim.x + threadIdx.x;
    if (i < N) off[i] = exc[i] + bsum[i >> 8];
    if (i == 0) off[N] = E;
}

__global__ void fill_kernel(const int* __restrict__ h, const int* __restrict__ t,
                            int* __restrict__ cur, int* __restrict__ csr_t, int E) {
    int e = blockIdx.x * blockDim.x + threadIdx.x;
    if (e >= E) return;
    int p = atomicAdd(&cur[h[e]], 1);
    csr_t[p] = t[e];
}

// ---------------- per-layer: invnx[n][f] = 1/max(||x_nf||,eps) ----------------
__global__ void norm_kernel(const float* __restrict__ x, float* __restrict__ invnx, int total) {
    int i = blockIdx.x * blockDim.x + threadIdx.x;
    if (i >= total) return;
    float v = x[i];
    float s = v * v;
#pragma unroll
    for (int o = 8; o >= 1; o >>= 1) s += __shfl_xor(s, o);
    if ((i & 15) == 0) invnx[i >> 4] = 1.0f / fmaxf(sqrtf(s), 1e-12f);
}

// ---------------- per-iteration: fused softmax/prob + dcol + tailscale + xs ----
// one wave per node n. lanes (k-slot = l>>2, factor = l&3) for the A pass;
// epilogue: every lane l writes xs[n*64+l] = bf16(x * dcol[n][l>>4]).
__global__ void dcol_prob_xs_kernel(const float* __restrict__ Acsr, const int* __restrict__ off,
                                    const float* __restrict__ x, const float* __restrict__ invnx,
                                    float* __restrict__ prob, float* __restrict__ dcol,
                                    float* __restrict__ tailscale, u16* __restrict__ xs, int N) {
    int gid = blockIdx.x * blockDim.x + threadIdx.x;
    int n = gid >> 6;
    if (n >= N) return;
    int l = gid & 63;
    int s = off[n], e = off[n + 1];
    float sumf = 0.f;
    for (int base = s; base < e; base += 16) {
        int k = base + (l >> 2);
        bool valid = k < e;
        float a = valid ? Acsr[(size_t)k * 4 + (l & 3)] : 0.f;
        float mx = a;
        mx = fmaxf(mx, __shfl_xor(mx, 1));
        mx = fmaxf(mx, __shfl_xor(mx, 2));
        float ex = __expf(a - mx);
        float se = ex;
        se += __shfl_xor(se, 1);
        se += __shfl_xor(se, 2);
        float p = ex / se;
        if (valid) {
            prob[(size_t)k * 4 + (l & 3)] = p;
            sumf += p;
        }
    }
#pragma unroll
    for (int o = 4; o <= 32; o <<= 1) sumf += __shfl_xor(sumf, o);
    // lane l holds rowsum for factor (l&3)
    float dn = rsqrtf(sumf);
    if (l < 4) {
        dcol[n * 4 + l] = dn;
        tailscale[n * 4 + l] = invnx[n * 4 + l] * sqrtf(sumf);  // invnx / dcol
    }
    float myd = __shfl(dn, l >> 4);  // dcol for the factor owning column l
    size_t idx = ((size_t)n << 6) + l;
    xs[idx] = f2bf(x[idx] * myd);
}

// One 64-lane wave per node, 8 edges per loop iteration.
// lane l: g = l>>4 (edge slot), m = l&15 (column quad: cols 4m..4m+3), f = m>>2.
// loop1: acc[j] = sum_k prob[k][f] * xs[t_k][j]  (xs pre-scaled by dcol[t])
// combine slots via shfl_xor(16,32); out[n] = dcol[n]*acc; head = out/||out_f||.
// loop2: A_csr[k][f] += sum_j head_j * tanh(xs[t_k][j]*tailscale[t_k][f])
__global__ void message_routing_kernel(const int* __restrict__ off, const int* __restrict__ csr_t,
                                       float* __restrict__ Acsr, const float* __restrict__ prob,
                                       const u16* __restrict__ xs, const float* __restrict__ tailscale,
                                       const float* __restrict__ dcol,
                                       float* __restrict__ out, int N, int doRouting) {
    int gid = blockIdx.x * blockDim.x + threadIdx.x;
    int n = gid >> 6;
    if (n >= N) return;
    int l = gid & 63;
    int g = l >> 4;
    int m = l & 15;
    int f = m >> 2;
    int s = off[n], e = off[n + 1];

    float a0 = 0.f, a1 = 0.f, a2 = 0.f, a3 = 0.f;
#pragma unroll 2
    for (int k = s; k < e; k += 8) {
        int e1 = k + g, e2 = e1 + 4;
        bool v1 = e1 < e, v2 = e2 < e;
        int c1 = v1 ? e1 : s;
        int c2 = v2 ? e2 : s;
        int t1 = csr_t[c1], t2 = csr_t[c2];
        float p1 = v1 ? prob[(size_t)c1 * 4 + f] : 0.f;
        float p2 = v2 ? prob[(size_t)c2 * 4 + f] : 0.f;
        const ushort4 x1 = *(const ushort4*)(xs + ((size_t)t1 << 6) + (m << 2));
        const ushort4 x2 = *(const ushort4*)(xs + ((size_t)t2 << 6) + (m << 2));
        a0 += p1 * bf2f(x1.x) + p2 * bf2f(x2.x);
        a1 += p1 * bf2f(x1.y) + p2 * bf2f(x2.y);
        a2 += p1 * bf2f(x1.z) + p2 * bf2f(x2.z);
        a3 += p1 * bf2f(x1.w) + p2 * bf2f(x2.w);
    }
    a0 += __shfl_xor(a0, 16); a1 += __shfl_xor(a1, 16);
    a2 += __shfl_xor(a2, 16); a3 += __shfl_xor(a3, 16);
    a0 += __shfl_xor(a0, 32); a1 += __shfl_xor(a1, 32);
    a2 += __shfl_xor(a2, 32); a3 += __shfl_xor(a3, 32);

    float dn = dcol[n * 4 + f];
    float o0 = a0 * dn, o1 = a1 * dn, o2 = a2 * dn, o3 = a3 * dn;
    if (l < 16) {
        *(float4*)(out + ((size_t)n << 6) + (m << 2)) = make_float4(o0, o1, o2, o3);
    }
    if (!doRouting) return;

    float ss = o0 * o0 + o1 * o1 + o2 * o2 + o3 * o3;
    ss += __shfl_xor(ss, 1);
    ss += __shfl_xor(ss, 2);
    float inv = 1.0f / fmaxf(sqrtf(ss), 1e-12f);
    float h0 = o0 * inv, h1 = o1 * inv, h2 = o2 * inv, h3 = o3 * inv;

#pragma unroll 2
    for (int k = s; k < e; k += 8) {
        int e1 = k + g, e2 = e1 + 4;
        bool v1 = e1 < e, v2 = e2 < e;
        int c1 = v1 ? e1 : s;
        int c2 = v2 ? e2 : s;
        int t1 = csr_t[c1], t2 = csr_t[c2];
        float ts1 = tailscale[t1 * 4 + f];
        float ts2 = tailscale[t2 * 4 + f];
        const ushort4 x1 = *(const ushort4*)(xs + ((size_t)t1 << 6) + (m << 2));
        const ushort4 x2 = *(const ushort4*)(xs + ((size_t)t2 << 6) + (m << 2));
        float d1 = h0 * ptanh(bf2f(x1.x) * ts1) + h1 * ptanh(bf2f(x1.y) * ts1)
                 + h2 * ptanh(bf2f(x1.z) * ts1) + h3 * ptanh(bf2f(x1.w) * ts1);
        float d2 = h0 * ptanh(bf2f(x2.x) * ts2) + h1 * ptanh(bf2f(x2.y) * ts2)
                 + h2 * ptanh(bf2f(x2.z) * ts2) + h3 * ptanh(bf2f(x2.w) * ts2);
        d1 += __shfl_xor(d1, 1); d1 += __shfl_xor(d1, 2);
        d2 += __shfl_xor(d2, 1); d2 += __shfl_xor(d2, 2);
        if ((m & 3) == 0) {
            if (v1) Acsr[(size_t)c1 * 4 + f] += d1;
            if (v2) Acsr[(size_t)c2 * 4 + f] += d2;
        }
    }
}

// acc += v; if final, acc = (acc + v) / 3
__global__ void acc_kernel(float* __restrict__ acc, const float* __restrict__ v, int n, int final_) {
    int i = blockIdx.x * blockDim.x + threadIdx.x;
    if (i >= n) return;
    float r = acc[i] + v[i];
    acc[i] = final_ ? r * (1.0f / 3.0f) : r;
}

extern "C" void kernel_launch(void* const* d_in, const int* in_sizes, int n_in,
                              void* d_out, int out_size, void* d_ws, size_t ws_size,
                              hipStream_t stream) {
    const float* user_emb = (const float*)d_in[0];
    const float* item_emb = (const float*)d_in[1];
    const int* h = (const int*)d_in[2];
    const int* t = (const int*)d_in[3];

    const int nu_elems = in_sizes[0];
    const int ni_elems = in_sizes[1];
    const int total = nu_elems + ni_elems;   // N * 64
    const int N = total / DEMB;
    const int E = in_sizes[2];
    const int nb = (N + 255) / 256;

    float* acc = (float*)d_out;

    // ---- workspace layout ----
    float* x        = (float*)d_ws;                    // total f32
    float* out      = x + (size_t)total;               // total f32
    float* Acsr     = out + (size_t)total;             // 4E f32
    float* prob     = Acsr + (size_t)4 * E;            // 4E f32
    float* dcol     = prob + (size_t)4 * E;            // 4N f32
    float* tailsc   = dcol + (size_t)4 * N;            // 4N f32
    float* invnx    = tailsc + (size_t)4 * N;          // 4N f32
    u16* xs         = (u16*)(invnx + (size_t)4 * N);   // total u16
    int* counts     = (int*)(xs + (size_t)total);      // N
    int* off        = counts + N;                      // N+4
    int* cur        = off + N + 4;                     // N
    int* exc        = cur + N;                         // N
    int* bsum       = exc + N;                         // nb (padded)
    int* csr_t      = bsum + ((nb + 3) & ~3);          // E

    const int BLK = 256;
    const int gE = (E + BLK - 1) / BLK;
    const int gTot = (total + BLK - 1) / BLK;
    const int gNodeWave = (N * 64 + BLK - 1) / BLK;

    init_A_kernel<<<gE, BLK, 0, stream>>>((float4*)Acsr, E);
    concat_copy_kernel<<<gTot, BLK, 0, stream>>>(user_emb, item_emb, x, acc, nu_elems, total);

    // CSR build
    hipMemsetAsync(counts, 0, (size_t)N * sizeof(int), stream);
    count_kernel<<<gE, BLK, 0, stream>>>(h, counts, E);
    scan1_kernel<<<nb, 256, 0, stream>>>(counts, exc, bsum, N);
    scan2_kernel<<<1, 64, 0, stream>>>(bsum, nb);
    scan3_kernel<<<(N + BLK - 1) / BLK, BLK, 0, stream>>>(exc, bsum, off, N, E);
    hipMemcpyAsync(cur, off, (size_t)N * sizeof(int), hipMemcpyDeviceToDevice, stream);
    fill_kernel<<<gE, BLK, 0, stream>>>(h, t, cur, csr_t, E);

    float* xb = x;
    float* ob = out;

    for (int layer = 0; layer < 2; ++layer) {
        norm_kernel<<<gTot, BLK, 0, stream>>>(xb, invnx, total);
        for (int it = 0; it < 2; ++it) {
            bool last = (layer == 1 && it == 1);
            dcol_prob_xs_kernel<<<gNodeWave, BLK, 0, stream>>>(Acsr, off, xb, invnx, prob,
                                                               dcol, tailsc, xs, N);
            message_routing_kernel<<<gNodeWave, BLK, 0, stream>>>(off, csr_t, Acsr, prob, xs,
                                                                  tailsc, dcol, ob, N,
                                                                  last ? 0 : 1);
        }
        acc_kernel<<<gTot, BLK, 0, stream>>>(acc, ob, total, layer == 1 ? 1 : 0);
        float* tmp = xb; xb = ob; ob = tmp;
    }
}